// Round 14
// baseline (4899.355 us; speedup 1.0000x reference)
//
#include <hip/hip_runtime.h>
#include <stdint.h>

typedef unsigned short u16;
typedef unsigned int u32;
typedef unsigned long long u64;
using f32x4 = __attribute__((ext_vector_type(4))) float;
using s16x8 = __attribute__((ext_vector_type(8))) short;
using h16x8 = __attribute__((ext_vector_type(8))) _Float16;

#define DI __device__ __forceinline__

constexpr int kV = 32000, kE = 512, kH = 1024, kM = 256;
constexpr int kB = 2, kT = 2048, kS = 512;  // kS = kT/STRIDE, STRIDE=4
constexpr u64 kWatchdogTicks = 200000000ull;  // ~2 s at 100 MHz realtime clock

DI u16 f2bf(float f) {
  u32 u = __float_as_uint(f);
  u32 r = (u + 0x7FFFu + ((u >> 16) & 1u)) >> 16;  // RNE
  return (u16)r;
}
DI float bf2f(u16 u) { return __uint_as_float(((u32)u) << 16); }
DI u16 f2h(float f) { _Float16 h = (_Float16)f; return __builtin_bit_cast(u16, h); }

DI void gload_lds16(const void* g, void* l) {
  __builtin_amdgcn_global_load_lds((const __attribute__((address_space(1))) void*)g,
                                   (__attribute__((address_space(3))) void*)l, 16, 0, 0);
}
DI bool wd_expired(u64 t0) {
  return (__builtin_amdgcn_s_memrealtime() - t0) > kWatchdogTicks;
}

// ---------------------------------------------------------------- converts
__global__ __launch_bounds__(256)
void k_cvt(const float* __restrict__ in, u16* __restrict__ out, int n) {
  const int step = gridDim.x * blockDim.x;
  for (int i = blockIdx.x * blockDim.x + threadIdx.x; i * 4 < n; i += step) {
    f32x4 v = *(const f32x4*)(in + (size_t)i * 4);
    ushort4 o;
    o.x = f2bf(v[0]); o.y = f2bf(v[1]); o.z = f2bf(v[2]); o.w = f2bf(v[3]);
    *(ushort4*)(out + (size_t)i * 4) = o;
  }
}

// f32 -> f16 (RNE)
__global__ __launch_bounds__(256)
void k_cvt16(const float* __restrict__ in, u16* __restrict__ out, int n) {
  const int step = gridDim.x * blockDim.x;
  for (int i = blockIdx.x * blockDim.x + threadIdx.x; i * 4 < n; i += step) {
    f32x4 v = *(const f32x4*)(in + (size_t)i * 4);
    ushort4 o;
    o.x = f2h(v[0]); o.y = f2h(v[1]); o.z = f2h(v[2]); o.w = f2h(v[3]);
    *(ushort4*)(out + (size_t)i * 4) = o;
  }
}

__global__ __launch_bounds__(128)
void k_embed(const int* __restrict__ ids, const float* __restrict__ W,
             u16* __restrict__ out) {
  const int tok = blockIdx.x;
  const int id = ids[tok];
  f32x4 v = ((const f32x4*)(W + (size_t)id * kE))[threadIdx.x];
  ushort4 o;
  o.x = f2bf(v[0]); o.y = f2bf(v[1]); o.z = f2bf(v[2]); o.w = f2bf(v[3]);
  ((ushort4*)(out + (size_t)tok * kE))[threadIdx.x] = o;
}

__global__ __launch_bounds__(256)
void k_stride_copy(const u16* __restrict__ in, u16* __restrict__ out, int rowlen) {
  const int row = blockIdx.x;
  const int b = row / kS, s = row - b * kS;
  const u16* src = in + ((size_t)b * kT + 4 * s) * rowlen;
  u16* dst = out + (size_t)row * rowlen;
  for (int i = threadIdx.x; i < rowlen / 2; i += blockDim.x)
    reinterpret_cast<u32*>(dst)[i] = reinterpret_cast<const u32*>(src)[i];
}

// ---------------------------------------------------------------- GEMM
template<int EPI>
__global__ __launch_bounds__(256)
void k_gemm(const u16* __restrict__ A, const u16* __restrict__ Bm,
            float* __restrict__ Cf, u16* __restrict__ Cb,
            const float* __restrict__ bias,
            int Mdim, int Ndim, int Kdim,
            long long sA, long long sB, long long sC,
            const float* __restrict__ addf, const float* __restrict__ mulf) {
  __shared__ __align__(16) u16 lA[128 * 32];
  __shared__ __align__(16) u16 lB[128 * 32];
  const int tid = threadIdx.x;
  const int bz = blockIdx.z;
  A += (long long)bz * sA;
  Bm += (long long)bz * sB;
  const long long coff = (long long)bz * sC;
  const int m0 = blockIdx.y * 128;
  const int n0 = blockIdx.x * 128;
  const int lane = tid & 63;
  const int wm = ((tid >> 6) >> 1) * 64;
  const int wn = ((tid >> 6) & 1) * 64;
  const int sr = tid >> 2;
  const int sc = (tid & 3) * 8;
  f32x4 acc[4][4] = {};
  for (int kt = 0; kt < Kdim; kt += 32) {
    gload_lds16(A + (long long)(m0 + sr) * Kdim + kt + sc,       &lA[tid * 8]);
    gload_lds16(A + (long long)(m0 + 64 + sr) * Kdim + kt + sc,  &lA[(tid + 256) * 8]);
    gload_lds16(Bm + (long long)(n0 + sr) * Kdim + kt + sc,      &lB[tid * 8]);
    gload_lds16(Bm + (long long)(n0 + 64 + sr) * Kdim + kt + sc, &lB[(tid + 256) * 8]);
    __syncthreads();
    s16x8 af[4], bfv[4];
    const int fro = lane & 15;
    const int fk = (lane >> 4) * 8;
#pragma unroll
    for (int f = 0; f < 4; f++) {
      af[f]  = *reinterpret_cast<const s16x8*>(&lA[(wm + f * 16 + fro) * 32 + fk]);
      bfv[f] = *reinterpret_cast<const s16x8*>(&lB[(wn + f * 16 + fro) * 32 + fk]);
    }
#pragma unroll
    for (int i = 0; i < 4; i++)
#pragma unroll
      for (int j = 0; j < 4; j++)
        acc[i][j] = __builtin_amdgcn_mfma_f32_16x16x32_bf16(af[i], bfv[j], acc[i][j], 0, 0, 0);
    __syncthreads();
  }
  const int crow = (lane >> 4) * 4;
  const int ccol = lane & 15;
#pragma unroll
  for (int i = 0; i < 4; i++) {
#pragma unroll
    for (int j = 0; j < 4; j++) {
      const int gn = n0 + wn + j * 16 + ccol;
      const float bs = bias ? bias[gn] : 0.0f;
#pragma unroll
      for (int r = 0; r < 4; r++) {
        const int gm = m0 + wm + i * 16 + crow + r;
        const long long off = coff + (long long)gm * Ndim + gn;
        float v = acc[i][j][r] + bs;
        if constexpr (EPI == 0) {
          Cf[off] = v;
        } else if constexpr (EPI == 1) {
          Cb[off] = f2bf(v);
        } else if constexpr (EPI == 2) {
          float uu = fmaxf(v, 0.0f);
          Cb[off] = f2bf(uu * uu);
        } else {
          float g = 1.0f / (1.0f + __expf(-v));
          Cb[off] = f2bf(addf[off] + g * mulf[off]);
        }
      }
    }
  }
}

// ---------------------------------------------------------------- GRU
// XCD-domain protocol = r8 best-known-good (tagged-h, nt polls, handshake
// with demotion, ONE barrier/step via lh double buffer, per-wave back-
// pressure, poll+wallclock watchdog). Compute engine restructured around
// the measured constraint "weights must stream":
//  - weights converted to f16 (10-bit mantissa >= bf16): the dot uses
//    (float)w*(float)h -> no separate convert chain (v_cvt folds/fma_mix)
//  - r+z gate rows (64 rows, 128 KB f16) are PERMANENTLY LDS-resident,
//    read directly each step (LDS pipe, ~270 GB/s/CU, no restage)
//  - n gate rows (64 KB) stream from L2 (loop-invariant register loads,
//    2 MB/XCD stays L2-hot) -> LDS, L2 and VALU pipes overlap.
__global__ __launch_bounds__(512, 1)
void k_gru(const float* __restrict__ xg, const u16* __restrict__ whh16,
           const float* __restrict__ bhh, u64* __restrict__ hbuf,
           u32* __restrict__ flags, u16* __restrict__ states) {
  __shared__ __align__(16) u16 lw[64 * 1024];   // r+z rows, f16, 128 KB
  __shared__ __align__(16) u16 lh16[2][1024];   // h_t f16, double buffer
  __shared__ u32 s_ticket, s_dec, s_res, s_bail;
  const int tid = threadIdx.x;
  const u64 wd0 = __builtin_amdgcn_s_memrealtime();
  u32 xcc;
  asm("s_getreg_b32 %0, hwreg(HW_REG_XCC_ID)" : "=s"(xcc));
  xcc &= 7u;
  if (tid == 0) {
    s_bail = 0u;
    u32 tk = atomicAdd(&flags[128 + xcc], 1u);
    if (tk == 31u) {  // 32nd WG on this XCD -> declare full
      u32 fidx = atomicAdd(&flags[136], 1u);
      if (fidx < 2u)
        __hip_atomic_store(&flags[140 + fidx], xcc + 1u, __ATOMIC_RELAXED, __HIP_MEMORY_SCOPE_AGENT);
    }
    s_ticket = tk;
    u32 d = 0;
    if (blockIdx.x == 0) {
      u32 polls = 0;
      for (;;) {
        if (__hip_atomic_load(&flags[136], __ATOMIC_RELAXED, __HIP_MEMORY_SCOPE_AGENT) >= 2u) {
          u32 a = __hip_atomic_load(&flags[140], __ATOMIC_RELAXED, __HIP_MEMORY_SCOPE_AGENT);
          u32 b = __hip_atomic_load(&flags[141], __ATOMIC_RELAXED, __HIP_MEMORY_SCOPE_AGENT);
          if (a && b) { d = 1u | ((a - 1u) << 8) | ((b - 1u) << 16); break; }
        }
        __builtin_amdgcn_s_sleep(1);
        if (++polls > 500000u || wd_expired(wd0)) { d = 2u; break; }  // fallback
      }
      __hip_atomic_store(&flags[137], d, __ATOMIC_RELAXED, __HIP_MEMORY_SCOPE_AGENT);
    } else {
      u32 polls = 0;
      while (!(d = __hip_atomic_load(&flags[137], __ATOMIC_RELAXED, __HIP_MEMORY_SCOPE_AGENT))) {
        __builtin_amdgcn_s_sleep(1);
        if (++polls > 1000000u || wd_expired(wd0)) { d = 2u; break; }
      }
    }
    s_dec = d;
  }
  __syncthreads();
  const u32 dec = s_dec, ticket = s_ticket;
  int batch = -1;
  u32 slice = 0;
  bool l2m = false;
  if ((dec & 0xFFu) == 1u) {
    const u32 d0 = (dec >> 8) & 0xFFu, d1 = (dec >> 16) & 0xFFu;
    if (xcc == d0 && ticket < 32u) { batch = 0; slice = ticket; l2m = true; }
    else if (xcc == d1 && ticket < 32u) { batch = 1; slice = ticket; l2m = true; }
  } else {
    if (blockIdx.x < 64u) { batch = (int)(blockIdx.x >> 5); slice = blockIdx.x & 31u; }
  }
  if (batch < 0) return;

  // ---- handshake (XCD mode): test plain-store -> nt-load L2 visibility
  if (l2m) {
    u32* hel = &flags[160 + batch * 32];
    u32* vot = &flags[224 + batch * 32];
    if (tid == 0) {
      u32 one = 1u;
      asm volatile("global_store_dword %0, %1, off" :: "v"(&hel[slice]), "v"(one) : "memory");
    }
    bool ok = true;
    if (tid < 32) {
      u32 v = 0, polls = 0;
      const u32* hp = &hel[tid];
      do {
        asm volatile("global_load_dword %0, %1, off nt\n\ts_waitcnt vmcnt(0)"
                     : "=v"(v) : "v"(hp) : "memory");
        if (v) break;
        if (wd_expired(wd0)) break;
      } while (++polls < 200000u);
      ok = (v != 0);
    }
    u64 bad = __ballot(tid < 32 && !ok);
    if (tid == 0)
      __hip_atomic_store(&vot[slice], bad ? 2u : 1u, __ATOMIC_RELAXED, __HIP_MEMORY_SCOPE_AGENT);
    bool vb = false;
    if (tid < 32) {
      u32 v = 0, polls = 0;
      while (!(v = __hip_atomic_load(&vot[tid], __ATOMIC_RELAXED, __HIP_MEMORY_SCOPE_AGENT)))
        if (++polls > 1000000u || wd_expired(wd0)) break;
      vb = (v != 1u);
    }
    u64 anybad = __ballot(tid < 32 && vb);
    if (tid == 0) s_res = (anybad == 0ull) ? 1u : 0u;
    __syncthreads();
    if (s_res == 0u) l2m = false;  // collective demotion to MALL atomics
  }

  // ---- stage r+z gate rows into LDS (once): 64 rows x 2 KB = 128 KB
  const int j0 = (int)slice * 32;
  const int grp = tid >> 4;   // 0..31 -> local output j
  const int gl = tid & 15;    // 16 lanes per output
  const int j = j0 + grp;
#pragma unroll
  for (int r = 0; r < 16; r++) {
    int fi = tid + 512 * r;          // 16B chunk id, 8192 total
    int rl = fi >> 7;                // 0..63: gate(0..1)*32 + j_local
    int ce = (fi & 127) * 8;         // f16 elem offset
    int gate = rl >> 5, jl = rl & 31;
    gload_lds16(whh16 + ((size_t)gate * kH + j0 + jl) * kH + ce, &lw[fi * 8]);
  }
  // n-gate row of this thread's output -> registers (loop-invariant)
  h16x8 wn8[8];
  {
    const _Float16* wnrow = (const _Float16*)(whh16 + (size_t)(2 * kH + j) * kH);
#pragma unroll
    for (int i = 0; i < 8; i++) wn8[i] = *(const h16x8*)&wnrow[8 * (gl + 16 * i)];
  }
  __syncthreads();

  const float bhr = bhh[j], bhz = bhh[kH + j], bhn = bhh[2 * kH + j];
  u32* fl = flags + batch * 64;
  const int fli = tid & 31;
  const float* xgb = xg + (size_t)batch * kT * 3 * kH;
  u16* stb = states + (size_t)batch * kT * kH;
  float hkeep = 0.0f;
  float gi_r = 0.0f, gi_z = 0.0f, gi_n = 0.0f;
  if (gl == 0) { gi_r = xgb[j]; gi_z = xgb[kH + j]; gi_n = xgb[2 * kH + j]; }
  bool bailed = false;
  const _Float16* lwr = (const _Float16*)&lw[(size_t)grp * 1024];
  const _Float16* lwz = (const _Float16*)&lw[(size_t)(32 + grp) * 1024];

  for (int t = 0; t < kT; t++) {
    u64* hc = hbuf + (size_t)(t & 1) * (kB * kH) + (size_t)batch * kH;
    u64* hn = hbuf + (size_t)((t + 1) & 1) * (kB * kH) + (size_t)batch * kH;
    const u32 want = (u32)t;
    const int par = t & 1;
    // ---- stage h_t: poll tagged atoms (2 per thread) -> f16 in LDS
    if (!bailed) {
      u64 v0 = 0, v1 = 0;
      u32 polls = 0;
      if (l2m) {
        const u64* p0 = hc + tid;
        const u64* p1 = hc + tid + 512;
        for (;;) {
          asm volatile(
              "global_load_dwordx2 %0, %2, off nt\n\t"
              "global_load_dwordx2 %1, %3, off nt\n\t"
              "s_waitcnt vmcnt(0)"
              : "=&v"(v0), "=&v"(v1) : "v"(p0), "v"(p1) : "memory");
          if ((u32)(v0 >> 32) >= want && (u32)(v1 >> 32) >= want) break;
          if (++polls > 400000u) { bailed = true; break; }
          if (!(polls & 4095u) && wd_expired(wd0)) { bailed = true; break; }
        }
      } else {
        for (;;) {
          v0 = __hip_atomic_load(hc + tid, __ATOMIC_RELAXED, __HIP_MEMORY_SCOPE_AGENT);
          v1 = __hip_atomic_load(hc + tid + 512, __ATOMIC_RELAXED, __HIP_MEMORY_SCOPE_AGENT);
          if ((u32)(v0 >> 32) >= want && (u32)(v1 >> 32) >= want) break;
          if (++polls > 400000u) { bailed = true; break; }
          if (!(polls & 4095u) && wd_expired(wd0)) { bailed = true; break; }
        }
      }
      lh16[par][tid] = f2h(__uint_as_float((u32)v0));
      lh16[par][tid + 512] = f2h(__uint_as_float((u32)v1));
    }
    if (bailed) s_bail = 1u;   // benign race
    __syncthreads();           // THE barrier: lh16 ready; all h_t reads done
    bailed = (s_bail != 0u);   // WG-wide sticky
    // release buffer parity for step-t+1 writers
    if (tid == 0) {
      u32 fv = (u32)(t + 1);
      if (l2m) asm volatile("global_store_dword %0, %1, off" :: "v"(&fl[slice]), "v"(fv) : "memory");
      else __hip_atomic_store(&fl[slice], fv, __ATOMIC_RELAXED, __HIP_MEMORY_SCOPE_AGENT);
    }
    // pre-issue backpressure flag read (all lanes; fl[tid&31])
    u32 myf = 0;
    if (!bailed) {
      if (l2m) asm volatile("global_load_dword %0, %1, off nt\n\ts_waitcnt vmcnt(0)"
                            : "=v"(myf) : "v"(&fl[fli]) : "memory");
      else myf = __hip_atomic_load(&fl[fli], __ATOMIC_RELAXED, __HIP_MEMORY_SCOPE_AGENT);
    }
    // ---- dots: r,z from LDS; n from registers; f16 x f16 -> f32 acc
    const _Float16* lhh = (const _Float16*)&lh16[par][0];
    float ar = 0.f, az = 0.f, an = 0.f;
#pragma unroll
    for (int i = 0; i < 8; i++) {
      const int k = 8 * (gl + 16 * i);
      h16x8 hv = *(const h16x8*)&lhh[k];
      h16x8 wr = *(const h16x8*)&lwr[k];
      h16x8 wz = *(const h16x8*)&lwz[k];
      h16x8 wn = wn8[i];
#pragma unroll
      for (int e = 0; e < 8; e++) {
        const float hf = (float)hv[e];
        ar += (float)wr[e] * hf;
        az += (float)wz[e] * hf;
        an += (float)wn[e] * hf;
      }
    }
#pragma unroll
    for (int m = 8; m >= 1; m >>= 1) {
      ar += __shfl_xor(ar, m, 16);
      az += __shfl_xor(az, m, 16);
      an += __shfl_xor(an, m, 16);
    }
    // ---- backpressure (per-wave): all domain flags >= t
    if (!bailed) {
      u32 polls = 0;
      while (__ballot(myf < want) != 0ull) {
        if (++polls > 400000u) { bailed = true; break; }
        if (!(polls & 4095u) && wd_expired(wd0)) { bailed = true; break; }
        if (l2m) asm volatile("global_load_dword %0, %1, off nt\n\ts_waitcnt vmcnt(0)"
                              : "=v"(myf) : "v"(&fl[fli]) : "memory");
        else myf = __hip_atomic_load(&fl[fli], __ATOMIC_RELAXED, __HIP_MEMORY_SCOPE_AGENT);
      }
    }
    if (gl == 0) {
      float r = 1.0f / (1.0f + __expf(-(gi_r + ar + bhr)));
      float z = 1.0f / (1.0f + __expf(-(gi_z + az + bhz)));
      float ex = __expf(2.0f * (gi_n + r * (an + bhn)));
      float n = (ex - 1.0f) / (ex + 1.0f);   // tanh
      float hnew = (1.0f - z) * n + z * hkeep;
      hkeep = hnew;
      u64 pk = ((u64)(u32)(t + 1) << 32) | (u64)__float_as_uint(hnew);
      if (l2m) asm volatile("global_store_dwordx2 %0, %1, off" :: "v"(hn + j), "v"(pk) : "memory");
      else __hip_atomic_store(hn + j, pk, __ATOMIC_RELAXED, __HIP_MEMORY_SCOPE_AGENT);
      stb[(size_t)t * kH + j] = f2bf(hnew);
      if (t + 1 < kT) {  // prefetch next xg (hides under next poll)
        const float* xp = xgb + (size_t)(t + 1) * 3 * kH;
        gi_r = xp[j]; gi_z = xp[kH + j]; gi_n = xp[2 * kH + j];
      }
    }
  }
}

// ---------------------------------------------------------------- softmax
__global__ __launch_bounds__(256)
void k_softmax(const float* __restrict__ sc, u16* __restrict__ att) {
  const int row = blockIdx.x * 4 + (threadIdx.x >> 6);
  const int lane = threadIdx.x & 63;
  const int t = row & (kT - 1);
  const int nv = (t + 3) >> 2;
  const float* src = sc + (long long)row * kS;
  u16* dst = att + (long long)row * kS;
  f32x4 v0 = *(const f32x4*)(src + lane * 8);
  f32x4 v1 = *(const f32x4*)(src + lane * 8 + 4);
  float x[8];
  float mx = -3.0e38f;
#pragma unroll
  for (int e = 0; e < 8; e++) {
    float val = ((e < 4) ? v0[e & 3] : v1[e & 3]) * 0.0625f;  // 1/sqrt(256)
    x[e] = val;
    if (lane * 8 + e < nv) mx = fmaxf(mx, val);
  }
#pragma unroll
  for (int m = 32; m >= 1; m >>= 1) mx = fmaxf(mx, __shfl_xor(mx, m, 64));
  float p[8];
  float sum = 0.0f;
#pragma unroll
  for (int e = 0; e < 8; e++) {
    p[e] = (lane * 8 + e < nv) ? __expf(x[e] - mx) : 0.0f;
    sum += p[e];
  }
#pragma unroll
  for (int m = 32; m >= 1; m >>= 1) sum += __shfl_xor(sum, m, 64);
  const float inv = (nv == 0) ? 0.0f : (1.0f / sum);
  ushort4 o0, o1;
  o0.x = f2bf(p[0] * inv); o0.y = f2bf(p[1] * inv);
  o0.z = f2bf(p[2] * inv); o0.w = f2bf(p[3] * inv);
  o1.x = f2bf(p[4] * inv); o1.y = f2bf(p[5] * inv);
  o1.z = f2bf(p[6] * inv); o1.w = f2bf(p[7] * inv);
  *(ushort4*)(dst + lane * 8) = o0;
  *(ushort4*)(dst + lane * 8 + 4) = o1;
}

// ---------------------------------------------------------------- host
static void gemm(int epi, const u16* A, const u16* Bm, float* Cf, u16* Cb,
                 const float* bias, int M, int N, int K, int batch,
                 long long sA, long long sB, long long sC,
                 const float* addf, const float* mulf, hipStream_t st) {
  dim3 g((unsigned)(N / 128), (unsigned)(M / 128), (unsigned)batch), b(256);
  switch (epi) {
    case 0: k_gemm<0><<<g, b, 0, st>>>(A, Bm, Cf, Cb, bias, M, N, K, sA, sB, sC, addf, mulf); break;
    case 1: k_gemm<1><<<g, b, 0, st>>>(A, Bm, Cf, Cb, bias, M, N, K, sA, sB, sC, addf, mulf); break;
    case 2: k_gemm<2><<<g, b, 0, st>>>(A, Bm, Cf, Cb, bias, M, N, K, sA, sB, sC, addf, mulf); break;
    default: k_gemm<3><<<g, b, 0, st>>>(A, Bm, Cf, Cb, bias, M, N, K, sA, sB, sC, addf, mulf); break;
  }
}

extern "C" void kernel_launch(void* const* d_in, const int* in_sizes, int n_in,
                              void* d_out, int out_size, void* d_ws, size_t ws_size,
                              hipStream_t stream) {
  (void)in_sizes; (void)n_in; (void)out_size;
  const int* ids      = (const int*)d_in[0];
  const float* embW   = (const float*)d_in[1];
  const float* w_ih   = (const float*)d_in[2];
  const float* w_hh   = (const float*)d_in[3];
  const float* b_ih   = (const float*)d_in[4];
  const float* b_hh   = (const float*)d_in[5];
  const float* q_w    = (const float*)d_in[6];
  const float* q_b    = (const float*)d_in[7];
  const float* k_w    = (const float*)d_in[8];
  const float* k_b    = (const float*)d_in[9];
  const float* hfc_w  = (const float*)d_in[10];
  const float* hfc_b  = (const float*)d_in[11];
  const float* hproj_w  = (const float*)d_in[12];
  const float* hproj_b  = (const float*)d_in[13];
  const float* v_w    = (const float*)d_in[14];
  const float* gate_w = (const float*)d_in[15];
  const float* gate_b = (const float*)d_in[16];
  const float* out_b  = (const float*)d_in[17];
  float* out = (float*)d_out;

  char* ws = (char*)d_ws;
  size_t off = 0;
  auto alloc = [&](size_t bytes) -> void* {
    void* p = ws + off;
    off += (bytes + 255) & ~(size_t)255;
    return p;
  };
  // ---- persistent region ----
  u16* embw_bf   = (u16*)alloc((size_t)kV * kE * 2);
  u16* states_bf = (u16*)alloc((size_t)kB * kT * kH * 2);
  u16* emb_bf    = (u16*)alloc((size_t)kB * kT * kE * 2);
  u16* qw_bf     = (u16*)alloc((size_t)kM * kH * 2);
  u16* kw_bf     = (u16*)alloc((size_t)kM * kH * 2);
  u16* hfcw_bf   = (u16*)alloc((size_t)4 * kE * kH * 2);
  u16* hprojw_bf = (u16*)alloc((size_t)kE * 4 * kE * 2);
  u16* vw_bf     = (u16*)alloc((size_t)kE * kE * 2);
  u16* gatew_bf  = (u16*)alloc((size_t)kE * kH * 2);
  u64* hbuf      = (u64*)alloc((size_t)2 * kB * kH * 8);   // 32 KB tagged h
  u32* flags     = (u32*)alloc(2048);                      // control block
  const size_t s0 = off;
  // ---- scratch layout G (GRU phase) ----
  u16* wih_bf    = (u16*)alloc((size_t)3 * kH * kE * 2);
  u16* whh_h16   = (u16*)alloc((size_t)3 * kH * kH * 2);
  float* xg      = (float*)alloc((size_t)kB * kT * 3 * kH * 4);
  const size_t endG = off;
  // ---- scratch layout A (attention phase; aliases G) ----
  off = s0;
  u16* head_bf   = (u16*)alloc((size_t)kB * kT * 4 * kE * 2);
  float* basef   = (float*)alloc((size_t)kB * kT * kE * 4);
  u16* qk_bf     = (u16*)alloc((size_t)kB * kT * kM * 2);
  u16* srcs_bf   = (u16*)alloc((size_t)kB * kS * kH * 2);
  u16* srcv_bf   = (u16*)alloc((size_t)kB * kS * kE * 2);
  u16* mk_bf     = (u16*)alloc((size_t)kB * kS * kM * 2);
  float* scoresf = (float*)alloc((size_t)kB * kT * kS * 4);
  u16* att_bf    = (u16*)alloc((size_t)kB * kT * kS * 2);
  u16* svt_bf    = (u16*)alloc((size_t)kB * kE * kS * 2);
  float* retrf   = (float*)alloc((size_t)kB * kT * kE * 4);
  u16* mixed_bf  = (u16*)alloc((size_t)kB * kT * kE * 2);
  const size_t endA = off;
  const size_t need = (endG > endA ? endG : endA);
  if (ws_size < need) return;  // clean failure instead of OOB wedge

  dim3 b256(256);
  k_cvt<<<1024, b256, 0, stream>>>(w_ih, wih_bf, 3 * kH * kE);
  k_cvt16<<<1024, b256, 0, stream>>>(w_hh, whh_h16, 3 * kH * kH);
  k_cvt<<<1024, b256, 0, stream>>>(q_w, qw_bf, kM * kH);
  k_cvt<<<1024, b256, 0, stream>>>(k_w, kw_bf, kM * kH);
  k_cvt<<<1024, b256, 0, stream>>>(hfc_w, hfcw_bf, 4 * kE * kH);
  k_cvt<<<1024, b256, 0, stream>>>(hproj_w, hprojw_bf, kE * 4 * kE);
  k_cvt<<<1024, b256, 0, stream>>>(v_w, vw_bf, kE * kE);
  k_cvt<<<1024, b256, 0, stream>>>(gate_w, gatew_bf, kE * kH);
  k_cvt<<<2048, b256, 0, stream>>>(embW, embw_bf, kV * kE);
  k_embed<<<kB * kT, 128, 0, stream>>>(ids, embW, emb_bf);

  // xg = emb @ w_ih^T + b_ih  (f32 out, feeds GRU)
  gemm(0, emb_bf, wih_bf, xg, nullptr, b_ih, kB * kT, 3 * kH, kE,
       1, 0, 0, 0, nullptr, nullptr, stream);

  // GRU scan; tagged h-buffer + control block zeroed (tag 0 == h_0 = 0.0)
  hipMemsetAsync(hbuf, 0, (size_t)2 * kB * kH * 8 + 2048, stream);
  k_gru<<<256, dim3(512), 0, stream>>>(xg, whh_h16, b_hh, hbuf, flags, states_bf);

  gemm(2, states_bf, hfcw_bf, nullptr, head_bf, hfc_b, kB * kT, 4 * kE, kH,
       1, 0, 0, 0, nullptr, nullptr, stream);
  gemm(0, head_bf, hprojw_bf, basef, nullptr, hproj_b, kB * kT, kE, 4 * kE,
       1, 0, 0, 0, nullptr, nullptr, stream);
  gemm(1, states_bf, qw_bf, nullptr, qk_bf, q_b, kB * kT, kM, kH,
       1, 0, 0, 0, nullptr, nullptr, stream);
  k_stride_copy<<<kB * kS, b256, 0, stream>>>(states_bf, srcs_bf, kH);
  k_stride_copy<<<kB * kS, b256, 0, stream>>>(emb_bf, srcv_bf, kE);
  gemm(1, srcs_bf, kw_bf, nullptr, mk_bf, k_b, kB * kS, kM, kH,
       1, 0, 0, 0, nullptr, nullptr, stream);
  gemm(0, qk_bf, mk_bf, scoresf, nullptr, nullptr, kT, kS, kM, kB,
       (long long)kT * kM, (long long)kS * kM, (long long)kT * kS,
       nullptr, nullptr, stream);
  k_softmax<<<(kB * kT) / 4, b256, 0, stream>>>(scoresf, att_bf);
  gemm(1, vw_bf, srcv_bf, nullptr, svt_bf, nullptr, kE, kS, kE, kB,
       0, (long long)kS * kE, (long long)kE * kS, nullptr, nullptr, stream);
  gemm(0, att_bf, svt_bf, retrf, nullptr, nullptr, kT, kE, kS, kB,
       (long long)kT * kS, (long long)kE * kS, (long long)kT * kE,
       nullptr, nullptr, stream);
  gemm(3, states_bf, gatew_bf, nullptr, mixed_bf, gate_b, kB * kT, kE, kH,
       1, 0, 0, 0, basef, retrf, stream);
  gemm(0, mixed_bf, embw_bf, out, nullptr, out_b, kB * kT, kV, kE,
       1, 0, 0, 0, nullptr, nullptr, stream);
}

// Round 15
// 4550.903 us; speedup vs baseline: 1.0766x; 1.0766x over previous
//
#include <hip/hip_runtime.h>
#include <stdint.h>

typedef unsigned short u16;
typedef unsigned int u32;
typedef unsigned long long u64;
using f32x4 = __attribute__((ext_vector_type(4))) float;
using s16x8 = __attribute__((ext_vector_type(8))) short;
using h16x8 = __attribute__((ext_vector_type(8))) _Float16;
using h16x2 = __attribute__((ext_vector_type(2))) _Float16;

#define DI __device__ __forceinline__

constexpr int kV = 32000, kE = 512, kH = 1024, kM = 256;
constexpr int kB = 2, kT = 2048, kS = 512;  // kS = kT/STRIDE, STRIDE=4
constexpr u64 kWatchdogTicks = 200000000ull;  // ~2 s at 100 MHz realtime clock

DI u16 f2bf(float f) {
  u32 u = __float_as_uint(f);
  u32 r = (u + 0x7FFFu + ((u >> 16) & 1u)) >> 16;  // RNE
  return (u16)r;
}
DI float bf2f(u16 u) { return __uint_as_float(((u32)u) << 16); }
DI u16 f2h(float f) { _Float16 h = (_Float16)f; return __builtin_bit_cast(u16, h); }

DI void gload_lds16(const void* g, void* l) {
  __builtin_amdgcn_global_load_lds((const __attribute__((address_space(1))) void*)g,
                                   (__attribute__((address_space(3))) void*)l, 16, 0, 0);
}
DI bool wd_expired(u64 t0) {
  return (__builtin_amdgcn_s_memrealtime() - t0) > kWatchdogTicks;
}

// ---------------------------------------------------------------- converts
__global__ __launch_bounds__(256)
void k_cvt(const float* __restrict__ in, u16* __restrict__ out, int n) {
  const int step = gridDim.x * blockDim.x;
  for (int i = blockIdx.x * blockDim.x + threadIdx.x; i * 4 < n; i += step) {
    f32x4 v = *(const f32x4*)(in + (size_t)i * 4);
    ushort4 o;
    o.x = f2bf(v[0]); o.y = f2bf(v[1]); o.z = f2bf(v[2]); o.w = f2bf(v[3]);
    *(ushort4*)(out + (size_t)i * 4) = o;
  }
}

// f32 -> f16 (RNE)
__global__ __launch_bounds__(256)
void k_cvt16(const float* __restrict__ in, u16* __restrict__ out, int n) {
  const int step = gridDim.x * blockDim.x;
  for (int i = blockIdx.x * blockDim.x + threadIdx.x; i * 4 < n; i += step) {
    f32x4 v = *(const f32x4*)(in + (size_t)i * 4);
    ushort4 o;
    o.x = f2h(v[0]); o.y = f2h(v[1]); o.z = f2h(v[2]); o.w = f2h(v[3]);
    *(ushort4*)(out + (size_t)i * 4) = o;
  }
}

__global__ __launch_bounds__(128)
void k_embed(const int* __restrict__ ids, const float* __restrict__ W,
             u16* __restrict__ out) {
  const int tok = blockIdx.x;
  const int id = ids[tok];
  f32x4 v = ((const f32x4*)(W + (size_t)id * kE))[threadIdx.x];
  ushort4 o;
  o.x = f2bf(v[0]); o.y = f2bf(v[1]); o.z = f2bf(v[2]); o.w = f2bf(v[3]);
  ((ushort4*)(out + (size_t)tok * kE))[threadIdx.x] = o;
}

__global__ __launch_bounds__(256)
void k_stride_copy(const u16* __restrict__ in, u16* __restrict__ out, int rowlen) {
  const int row = blockIdx.x;
  const int b = row / kS, s = row - b * kS;
  const u16* src = in + ((size_t)b * kT + 4 * s) * rowlen;
  u16* dst = out + (size_t)row * rowlen;
  for (int i = threadIdx.x; i < rowlen / 2; i += blockDim.x)
    reinterpret_cast<u32*>(dst)[i] = reinterpret_cast<const u32*>(src)[i];
}

// ---------------------------------------------------------------- GEMM
template<int EPI>
__global__ __launch_bounds__(256)
void k_gemm(const u16* __restrict__ A, const u16* __restrict__ Bm,
            float* __restrict__ Cf, u16* __restrict__ Cb,
            const float* __restrict__ bias,
            int Mdim, int Ndim, int Kdim,
            long long sA, long long sB, long long sC,
            const float* __restrict__ addf, const float* __restrict__ mulf) {
  __shared__ __align__(16) u16 lA[128 * 32];
  __shared__ __align__(16) u16 lB[128 * 32];
  const int tid = threadIdx.x;
  const int bz = blockIdx.z;
  A += (long long)bz * sA;
  Bm += (long long)bz * sB;
  const long long coff = (long long)bz * sC;
  const int m0 = blockIdx.y * 128;
  const int n0 = blockIdx.x * 128;
  const int lane = tid & 63;
  const int wm = ((tid >> 6) >> 1) * 64;
  const int wn = ((tid >> 6) & 1) * 64;
  const int sr = tid >> 2;
  const int sc = (tid & 3) * 8;
  f32x4 acc[4][4] = {};
  for (int kt = 0; kt < Kdim; kt += 32) {
    gload_lds16(A + (long long)(m0 + sr) * Kdim + kt + sc,       &lA[tid * 8]);
    gload_lds16(A + (long long)(m0 + 64 + sr) * Kdim + kt + sc,  &lA[(tid + 256) * 8]);
    gload_lds16(Bm + (long long)(n0 + sr) * Kdim + kt + sc,      &lB[tid * 8]);
    gload_lds16(Bm + (long long)(n0 + 64 + sr) * Kdim + kt + sc, &lB[(tid + 256) * 8]);
    __syncthreads();
    s16x8 af[4], bfv[4];
    const int fro = lane & 15;
    const int fk = (lane >> 4) * 8;
#pragma unroll
    for (int f = 0; f < 4; f++) {
      af[f]  = *reinterpret_cast<const s16x8*>(&lA[(wm + f * 16 + fro) * 32 + fk]);
      bfv[f] = *reinterpret_cast<const s16x8*>(&lB[(wn + f * 16 + fro) * 32 + fk]);
    }
#pragma unroll
    for (int i = 0; i < 4; i++)
#pragma unroll
      for (int j = 0; j < 4; j++)
        acc[i][j] = __builtin_amdgcn_mfma_f32_16x16x32_bf16(af[i], bfv[j], acc[i][j], 0, 0, 0);
    __syncthreads();
  }
  const int crow = (lane >> 4) * 4;
  const int ccol = lane & 15;
#pragma unroll
  for (int i = 0; i < 4; i++) {
#pragma unroll
    for (int j = 0; j < 4; j++) {
      const int gn = n0 + wn + j * 16 + ccol;
      const float bs = bias ? bias[gn] : 0.0f;
#pragma unroll
      for (int r = 0; r < 4; r++) {
        const int gm = m0 + wm + i * 16 + crow + r;
        const long long off = coff + (long long)gm * Ndim + gn;
        float v = acc[i][j][r] + bs;
        if constexpr (EPI == 0) {
          Cf[off] = v;
        } else if constexpr (EPI == 1) {
          Cb[off] = f2bf(v);
        } else if constexpr (EPI == 2) {
          float uu = fmaxf(v, 0.0f);
          Cb[off] = f2bf(uu * uu);
        } else {
          float g = 1.0f / (1.0f + __expf(-v));
          Cb[off] = f2bf(addf[off] + g * mulf[off]);
        }
      }
    }
  }
}

// ---------------------------------------------------------------- GRU
// XCD-domain protocol = r8 best-known-good (tagged-h, nt polls, handshake
// with demotion, ONE barrier/step via lh double buffer, per-wave back-
// pressure, poll+wallclock watchdog). Compute engine: v_dot2_f32_f16
// (__builtin_amdgcn_fdot2) -> 2 f16 MACs + f32 accum per instruction,
// zero converts. r+z gate rows (128 KB f16) LDS-resident; n-gate rows
// stream from L2 with loads ISSUED BEFORE the r/z dot (latency hidden
// under LDS reads; L2/LDS/VALU pipes overlap). h cached in 32 VGPRs.
__global__ __launch_bounds__(512, 1)
void k_gru(const float* __restrict__ xg, const u16* __restrict__ whh16,
           const float* __restrict__ bhh, u64* __restrict__ hbuf,
           u32* __restrict__ flags, u16* __restrict__ states) {
  __shared__ __align__(16) u16 lw[64 * 1024];   // r+z rows, f16, 128 KB
  __shared__ __align__(16) u16 lh16[2][1024];   // h_t f16, double buffer
  __shared__ u32 s_ticket, s_dec, s_res, s_bail;
  const int tid = threadIdx.x;
  const u64 wd0 = __builtin_amdgcn_s_memrealtime();
  u32 xcc;
  asm("s_getreg_b32 %0, hwreg(HW_REG_XCC_ID)" : "=s"(xcc));
  xcc &= 7u;
  if (tid == 0) {
    s_bail = 0u;
    u32 tk = atomicAdd(&flags[128 + xcc], 1u);
    if (tk == 31u) {  // 32nd WG on this XCD -> declare full
      u32 fidx = atomicAdd(&flags[136], 1u);
      if (fidx < 2u)
        __hip_atomic_store(&flags[140 + fidx], xcc + 1u, __ATOMIC_RELAXED, __HIP_MEMORY_SCOPE_AGENT);
    }
    s_ticket = tk;
    u32 d = 0;
    if (blockIdx.x == 0) {
      u32 polls = 0;
      for (;;) {
        if (__hip_atomic_load(&flags[136], __ATOMIC_RELAXED, __HIP_MEMORY_SCOPE_AGENT) >= 2u) {
          u32 a = __hip_atomic_load(&flags[140], __ATOMIC_RELAXED, __HIP_MEMORY_SCOPE_AGENT);
          u32 b = __hip_atomic_load(&flags[141], __ATOMIC_RELAXED, __HIP_MEMORY_SCOPE_AGENT);
          if (a && b) { d = 1u | ((a - 1u) << 8) | ((b - 1u) << 16); break; }
        }
        __builtin_amdgcn_s_sleep(1);
        if (++polls > 500000u || wd_expired(wd0)) { d = 2u; break; }  // fallback
      }
      __hip_atomic_store(&flags[137], d, __ATOMIC_RELAXED, __HIP_MEMORY_SCOPE_AGENT);
    } else {
      u32 polls = 0;
      while (!(d = __hip_atomic_load(&flags[137], __ATOMIC_RELAXED, __HIP_MEMORY_SCOPE_AGENT))) {
        __builtin_amdgcn_s_sleep(1);
        if (++polls > 1000000u || wd_expired(wd0)) { d = 2u; break; }
      }
    }
    s_dec = d;
  }
  __syncthreads();
  const u32 dec = s_dec, ticket = s_ticket;
  int batch = -1;
  u32 slice = 0;
  bool l2m = false;
  if ((dec & 0xFFu) == 1u) {
    const u32 d0 = (dec >> 8) & 0xFFu, d1 = (dec >> 16) & 0xFFu;
    if (xcc == d0 && ticket < 32u) { batch = 0; slice = ticket; l2m = true; }
    else if (xcc == d1 && ticket < 32u) { batch = 1; slice = ticket; l2m = true; }
  } else {
    if (blockIdx.x < 64u) { batch = (int)(blockIdx.x >> 5); slice = blockIdx.x & 31u; }
  }
  if (batch < 0) return;

  // ---- handshake (XCD mode): test plain-store -> nt-load L2 visibility
  if (l2m) {
    u32* hel = &flags[160 + batch * 32];
    u32* vot = &flags[224 + batch * 32];
    if (tid == 0) {
      u32 one = 1u;
      asm volatile("global_store_dword %0, %1, off" :: "v"(&hel[slice]), "v"(one) : "memory");
    }
    bool ok = true;
    if (tid < 32) {
      u32 v = 0, polls = 0;
      const u32* hp = &hel[tid];
      do {
        asm volatile("global_load_dword %0, %1, off nt\n\ts_waitcnt vmcnt(0)"
                     : "=v"(v) : "v"(hp) : "memory");
        if (v) break;
        if (wd_expired(wd0)) break;
      } while (++polls < 200000u);
      ok = (v != 0);
    }
    u64 bad = __ballot(tid < 32 && !ok);
    if (tid == 0)
      __hip_atomic_store(&vot[slice], bad ? 2u : 1u, __ATOMIC_RELAXED, __HIP_MEMORY_SCOPE_AGENT);
    bool vb = false;
    if (tid < 32) {
      u32 v = 0, polls = 0;
      while (!(v = __hip_atomic_load(&vot[tid], __ATOMIC_RELAXED, __HIP_MEMORY_SCOPE_AGENT)))
        if (++polls > 1000000u || wd_expired(wd0)) break;
      vb = (v != 1u);
    }
    u64 anybad = __ballot(tid < 32 && vb);
    if (tid == 0) s_res = (anybad == 0ull) ? 1u : 0u;
    __syncthreads();
    if (s_res == 0u) l2m = false;  // collective demotion to MALL atomics
  }

  // ---- stage r+z gate rows into LDS (once): 64 rows x 2 KB = 128 KB
  const int j0 = (int)slice * 32;
  const int grp = tid >> 4;   // 0..31 -> local output j
  const int gl = tid & 15;    // 16 lanes per output
  const int j = j0 + grp;
#pragma unroll
  for (int r = 0; r < 16; r++) {
    int fi = tid + 512 * r;          // 16B chunk id, 8192 total
    int rl = fi >> 7;                // 0..63: gate(0..1)*32 + j_local
    int ce = (fi & 127) * 8;         // f16 elem offset
    int gate = rl >> 5, jl = rl & 31;
    gload_lds16(whh16 + ((size_t)gate * kH + j0 + jl) * kH + ce, &lw[fi * 8]);
  }
  __syncthreads();

  const float bhr = bhh[j], bhz = bhh[kH + j], bhn = bhh[2 * kH + j];
  u32* fl = flags + batch * 64;
  const int fli = tid & 31;
  const float* xgb = xg + (size_t)batch * kT * 3 * kH;
  u16* stb = states + (size_t)batch * kT * kH;
  float hkeep = 0.0f;
  float gi_r = 0.0f, gi_z = 0.0f, gi_n = 0.0f;
  if (gl == 0) { gi_r = xgb[j]; gi_z = xgb[kH + j]; gi_n = xgb[2 * kH + j]; }
  bool bailed = false;
  const _Float16* lwr = (const _Float16*)&lw[(size_t)grp * 1024];
  const _Float16* lwz = (const _Float16*)&lw[(size_t)(32 + grp) * 1024];
  const _Float16* wnrow = (const _Float16*)(whh16 + (size_t)(2 * kH + j) * kH);

  for (int t = 0; t < kT; t++) {
    u64* hc = hbuf + (size_t)(t & 1) * (kB * kH) + (size_t)batch * kH;
    u64* hn = hbuf + (size_t)((t + 1) & 1) * (kB * kH) + (size_t)batch * kH;
    const u32 want = (u32)t;
    const int par = t & 1;
    // ---- stage h_t: poll tagged atoms (2 per thread) -> f16 in LDS
    if (!bailed) {
      u64 v0 = 0, v1 = 0;
      u32 polls = 0;
      if (l2m) {
        const u64* p0 = hc + tid;
        const u64* p1 = hc + tid + 512;
        for (;;) {
          asm volatile(
              "global_load_dwordx2 %0, %2, off nt\n\t"
              "global_load_dwordx2 %1, %3, off nt\n\t"
              "s_waitcnt vmcnt(0)"
              : "=&v"(v0), "=&v"(v1) : "v"(p0), "v"(p1) : "memory");
          if ((u32)(v0 >> 32) >= want && (u32)(v1 >> 32) >= want) break;
          if (++polls > 400000u) { bailed = true; break; }
          if (!(polls & 4095u) && wd_expired(wd0)) { bailed = true; break; }
        }
      } else {
        for (;;) {
          v0 = __hip_atomic_load(hc + tid, __ATOMIC_RELAXED, __HIP_MEMORY_SCOPE_AGENT);
          v1 = __hip_atomic_load(hc + tid + 512, __ATOMIC_RELAXED, __HIP_MEMORY_SCOPE_AGENT);
          if ((u32)(v0 >> 32) >= want && (u32)(v1 >> 32) >= want) break;
          if (++polls > 400000u) { bailed = true; break; }
          if (!(polls & 4095u) && wd_expired(wd0)) { bailed = true; break; }
        }
      }
      lh16[par][tid] = f2h(__uint_as_float((u32)v0));
      lh16[par][tid + 512] = f2h(__uint_as_float((u32)v1));
    }
    if (bailed) s_bail = 1u;   // benign race
    __syncthreads();           // THE barrier: lh16 ready; all h_t reads done
    bailed = (s_bail != 0u);   // WG-wide sticky
    // release buffer parity for step-t+1 writers
    if (tid == 0) {
      u32 fv = (u32)(t + 1);
      if (l2m) asm volatile("global_store_dword %0, %1, off" :: "v"(&fl[slice]), "v"(fv) : "memory");
      else __hip_atomic_store(&fl[slice], fv, __ATOMIC_RELAXED, __HIP_MEMORY_SCOPE_AGENT);
    }
    // pre-issue backpressure flag read (all lanes; fl[tid&31])
    u32 myf = 0;
    if (!bailed) {
      if (l2m) asm volatile("global_load_dword %0, %1, off nt\n\ts_waitcnt vmcnt(0)"
                            : "=v"(myf) : "v"(&fl[fli]) : "memory");
      else myf = __hip_atomic_load(&fl[fli], __ATOMIC_RELAXED, __HIP_MEMORY_SCOPE_AGENT);
    }
    // ---- n-gate loads issued EARLY (L2-hot); consumed after r/z dot
    h16x8 wn[8];
#pragma unroll
    for (int i = 0; i < 8; i++) wn[i] = *(const h16x8*)&wnrow[8 * (gl + 16 * i)];
    // ---- r,z dots from LDS via v_dot2_f32_f16 (h cached in VGPRs)
    const _Float16* lhh = (const _Float16*)&lh16[par][0];
    h16x8 hv[8];
#pragma unroll
    for (int i = 0; i < 8; i++) hv[i] = *(const h16x8*)&lhh[8 * (gl + 16 * i)];
    float ar = 0.f, az = 0.f, an = 0.f;
#pragma unroll
    for (int i = 0; i < 8; i++) {
      const int k = 8 * (gl + 16 * i);
      h16x8 wr = *(const h16x8*)&lwr[k];
      h16x8 wz = *(const h16x8*)&lwz[k];
      const h16x2* hv2 = (const h16x2*)&hv[i];
      const h16x2* wr2 = (const h16x2*)&wr;
      const h16x2* wz2 = (const h16x2*)&wz;
#pragma unroll
      for (int e = 0; e < 4; e++) {
        ar = __builtin_amdgcn_fdot2(wr2[e], hv2[e], ar, false);
        az = __builtin_amdgcn_fdot2(wz2[e], hv2[e], az, false);
      }
    }
#pragma unroll
    for (int i = 0; i < 8; i++) {
      const h16x2* hv2 = (const h16x2*)&hv[i];
      const h16x2* wn2 = (const h16x2*)&wn[i];
#pragma unroll
      for (int e = 0; e < 4; e++)
        an = __builtin_amdgcn_fdot2(wn2[e], hv2[e], an, false);
    }
#pragma unroll
    for (int m = 8; m >= 1; m >>= 1) {
      ar += __shfl_xor(ar, m, 16);
      az += __shfl_xor(az, m, 16);
      an += __shfl_xor(an, m, 16);
    }
    // ---- backpressure (per-wave): all domain flags >= t
    if (!bailed) {
      u32 polls = 0;
      while (__ballot(myf < want) != 0ull) {
        if (++polls > 400000u) { bailed = true; break; }
        if (!(polls & 4095u) && wd_expired(wd0)) { bailed = true; break; }
        if (l2m) asm volatile("global_load_dword %0, %1, off nt\n\ts_waitcnt vmcnt(0)"
                              : "=v"(myf) : "v"(&fl[fli]) : "memory");
        else myf = __hip_atomic_load(&fl[fli], __ATOMIC_RELAXED, __HIP_MEMORY_SCOPE_AGENT);
      }
    }
    if (gl == 0) {
      float r = 1.0f / (1.0f + __expf(-(gi_r + ar + bhr)));
      float z = 1.0f / (1.0f + __expf(-(gi_z + az + bhz)));
      float ex = __expf(2.0f * (gi_n + r * (an + bhn)));
      float n = (ex - 1.0f) / (ex + 1.0f);   // tanh
      float hnew = (1.0f - z) * n + z * hkeep;
      hkeep = hnew;
      u64 pk = ((u64)(u32)(t + 1) << 32) | (u64)__float_as_uint(hnew);
      if (l2m) asm volatile("global_store_dwordx2 %0, %1, off" :: "v"(hn + j), "v"(pk) : "memory");
      else __hip_atomic_store(hn + j, pk, __ATOMIC_RELAXED, __HIP_MEMORY_SCOPE_AGENT);
      stb[(size_t)t * kH + j] = f2bf(hnew);
      if (t + 1 < kT) {  // prefetch next xg (hides under next poll)
        const float* xp = xgb + (size_t)(t + 1) * 3 * kH;
        gi_r = xp[j]; gi_z = xp[kH + j]; gi_n = xp[2 * kH + j];
      }
    }
  }
}

// ---------------------------------------------------------------- softmax
__global__ __launch_bounds__(256)
void k_softmax(const float* __restrict__ sc, u16* __restrict__ att) {
  const int row = blockIdx.x * 4 + (threadIdx.x >> 6);
  const int lane = threadIdx.x & 63;
  const int t = row & (kT - 1);
  const int nv = (t + 3) >> 2;
  const float* src = sc + (long long)row * kS;
  u16* dst = att + (long long)row * kS;
  f32x4 v0 = *(const f32x4*)(src + lane * 8);
  f32x4 v1 = *(const f32x4*)(src + lane * 8 + 4);
  float x[8];
  float mx = -3.0e38f;
#pragma unroll
  for (int e = 0; e < 8; e++) {
    float val = ((e < 4) ? v0[e & 3] : v1[e & 3]) * 0.0625f;  // 1/sqrt(256)
    x[e] = val;
    if (lane * 8 + e < nv) mx = fmaxf(mx, val);
  }
#pragma unroll
  for (int m = 32; m >= 1; m >>= 1) mx = fmaxf(mx, __shfl_xor(mx, m, 64));
  float p[8];
  float sum = 0.0f;
#pragma unroll
  for (int e = 0; e < 8; e++) {
    p[e] = (lane * 8 + e < nv) ? __expf(x[e] - mx) : 0.0f;
    sum += p[e];
  }
#pragma unroll
  for (int m = 32; m >= 1; m >>= 1) sum += __shfl_xor(sum, m, 64);
  const float inv = (nv == 0) ? 0.0f : (1.0f / sum);
  ushort4 o0, o1;
  o0.x = f2bf(p[0] * inv); o0.y = f2bf(p[1] * inv);
  o0.z = f2bf(p[2] * inv); o0.w = f2bf(p[3] * inv);
  o1.x = f2bf(p[4] * inv); o1.y = f2bf(p[5] * inv);
  o1.z = f2bf(p[6] * inv); o1.w = f2bf(p[7] * inv);
  *(ushort4*)(dst + lane * 8) = o0;
  *(ushort4*)(dst + lane * 8 + 4) = o1;
}

// ---------------------------------------------------------------- host
static void gemm(int epi, const u16* A, const u16* Bm, float* Cf, u16* Cb,
                 const float* bias, int M, int N, int K, int batch,
                 long long sA, long long sB, long long sC,
                 const float* addf, const float* mulf, hipStream_t st) {
  dim3 g((unsigned)(N / 128), (unsigned)(M / 128), (unsigned)batch), b(256);
  switch (epi) {
    case 0: k_gemm<0><<<g, b, 0, st>>>(A, Bm, Cf, Cb, bias, M, N, K, sA, sB, sC, addf, mulf); break;
    case 1: k_gemm<1><<<g, b, 0, st>>>(A, Bm, Cf, Cb, bias, M, N, K, sA, sB, sC, addf, mulf); break;
    case 2: k_gemm<2><<<g, b, 0, st>>>(A, Bm, Cf, Cb, bias, M, N, K, sA, sB, sC, addf, mulf); break;
    default: k_gemm<3><<<g, b, 0, st>>>(A, Bm, Cf, Cb, bias, M, N, K, sA, sB, sC, addf, mulf); break;
  }
}

extern "C" void kernel_launch(void* const* d_in, const int* in_sizes, int n_in,
                              void* d_out, int out_size, void* d_ws, size_t ws_size,
                              hipStream_t stream) {
  (void)in_sizes; (void)n_in; (void)out_size;
  const int* ids      = (const int*)d_in[0];
  const float* embW   = (const float*)d_in[1];
  const float* w_ih   = (const float*)d_in[2];
  const float* w_hh   = (const float*)d_in[3];
  const float* b_ih   = (const float*)d_in[4];
  const float* b_hh   = (const float*)d_in[5];
  const float* q_w    = (const float*)d_in[6];
  const float* q_b    = (const float*)d_in[7];
  const float* k_w    = (const float*)d_in[8];
  const float* k_b    = (const float*)d_in[9];
  const float* hfc_w  = (const float*)d_in[10];
  const float* hfc_b  = (const float*)d_in[11];
  const float* hproj_w  = (const float*)d_in[12];
  const float* hproj_b  = (const float*)d_in[13];
  const float* v_w    = (const float*)d_in[14];
  const float* gate_w = (const float*)d_in[15];
  const float* gate_b = (const float*)d_in[16];
  const float* out_b  = (const float*)d_in[17];
  float* out = (float*)d_out;

  char* ws = (char*)d_ws;
  size_t off = 0;
  auto alloc = [&](size_t bytes) -> void* {
    void* p = ws + off;
    off += (bytes + 255) & ~(size_t)255;
    return p;
  };
  // ---- persistent region ----
  u16* embw_bf   = (u16*)alloc((size_t)kV * kE * 2);
  u16* states_bf = (u16*)alloc((size_t)kB * kT * kH * 2);
  u16* emb_bf    = (u16*)alloc((size_t)kB * kT * kE * 2);
  u16* qw_bf     = (u16*)alloc((size_t)kM * kH * 2);
  u16* kw_bf     = (u16*)alloc((size_t)kM * kH * 2);
  u16* hfcw_bf   = (u16*)alloc((size_t)4 * kE * kH * 2);
  u16* hprojw_bf = (u16*)alloc((size_t)kE * 4 * kE * 2);
  u16* vw_bf     = (u16*)alloc((size_t)kE * kE * 2);
  u16* gatew_bf  = (u16*)alloc((size_t)kE * kH * 2);
  u64* hbuf      = (u64*)alloc((size_t)2 * kB * kH * 8);   // 32 KB tagged h
  u32* flags     = (u32*)alloc(2048);                      // control block
  const size_t s0 = off;
  // ---- scratch layout G (GRU phase) ----
  u16* wih_bf    = (u16*)alloc((size_t)3 * kH * kE * 2);
  u16* whh_h16   = (u16*)alloc((size_t)3 * kH * kH * 2);
  float* xg      = (float*)alloc((size_t)kB * kT * 3 * kH * 4);
  const size_t endG = off;
  // ---- scratch layout A (attention phase; aliases G) ----
  off = s0;
  u16* head_bf   = (u16*)alloc((size_t)kB * kT * 4 * kE * 2);
  float* basef   = (float*)alloc((size_t)kB * kT * kE * 4);
  u16* qk_bf     = (u16*)alloc((size_t)kB * kT * kM * 2);
  u16* srcs_bf   = (u16*)alloc((size_t)kB * kS * kH * 2);
  u16* srcv_bf   = (u16*)alloc((size_t)kB * kS * kE * 2);
  u16* mk_bf     = (u16*)alloc((size_t)kB * kS * kM * 2);
  float* scoresf = (float*)alloc((size_t)kB * kT * kS * 4);
  u16* att_bf    = (u16*)alloc((size_t)kB * kT * kS * 2);
  u16* svt_bf    = (u16*)alloc((size_t)kB * kE * kS * 2);
  float* retrf   = (float*)alloc((size_t)kB * kT * kE * 4);
  u16* mixed_bf  = (u16*)alloc((size_t)kB * kT * kE * 2);
  const size_t endA = off;
  const size_t need = (endG > endA ? endG : endA);
  if (ws_size < need) return;  // clean failure instead of OOB wedge

  dim3 b256(256);
  k_cvt<<<1024, b256, 0, stream>>>(w_ih, wih_bf, 3 * kH * kE);
  k_cvt16<<<1024, b256, 0, stream>>>(w_hh, whh_h16, 3 * kH * kH);
  k_cvt<<<1024, b256, 0, stream>>>(q_w, qw_bf, kM * kH);
  k_cvt<<<1024, b256, 0, stream>>>(k_w, kw_bf, kM * kH);
  k_cvt<<<1024, b256, 0, stream>>>(hfc_w, hfcw_bf, 4 * kE * kH);
  k_cvt<<<1024, b256, 0, stream>>>(hproj_w, hprojw_bf, kE * 4 * kE);
  k_cvt<<<1024, b256, 0, stream>>>(v_w, vw_bf, kE * kE);
  k_cvt<<<1024, b256, 0, stream>>>(gate_w, gatew_bf, kE * kH);
  k_cvt<<<2048, b256, 0, stream>>>(embW, embw_bf, kV * kE);
  k_embed<<<kB * kT, 128, 0, stream>>>(ids, embW, emb_bf);

  // xg = emb @ w_ih^T + b_ih  (f32 out, feeds GRU)
  gemm(0, emb_bf, wih_bf, xg, nullptr, b_ih, kB * kT, 3 * kH, kE,
       1, 0, 0, 0, nullptr, nullptr, stream);

  // GRU scan; tagged h-buffer + control block zeroed (tag 0 == h_0 = 0.0)
  hipMemsetAsync(hbuf, 0, (size_t)2 * kB * kH * 8 + 2048, stream);
  k_gru<<<256, dim3(512), 0, stream>>>(xg, whh_h16, b_hh, hbuf, flags, states_bf);

  gemm(2, states_bf, hfcw_bf, nullptr, head_bf, hfc_b, kB * kT, 4 * kE, kH,
       1, 0, 0, 0, nullptr, nullptr, stream);
  gemm(0, head_bf, hprojw_bf, basef, nullptr, hproj_b, kB * kT, kE, 4 * kE,
       1, 0, 0, 0, nullptr, nullptr, stream);
  gemm(1, states_bf, qw_bf, nullptr, qk_bf, q_b, kB * kT, kM, kH,
       1, 0, 0, 0, nullptr, nullptr, stream);
  k_stride_copy<<<kB * kS, b256, 0, stream>>>(states_bf, srcs_bf, kH);
  k_stride_copy<<<kB * kS, b256, 0, stream>>>(emb_bf, srcv_bf, kE);
  gemm(1, srcs_bf, kw_bf, nullptr, mk_bf, k_b, kB * kS, kM, kH,
       1, 0, 0, 0, nullptr, nullptr, stream);
  gemm(0, qk_bf, mk_bf, scoresf, nullptr, nullptr, kT, kS, kM, kB,
       (long long)kT * kM, (long long)kS * kM, (long long)kT * kS,
       nullptr, nullptr, stream);
  k_softmax<<<(kB * kT) / 4, b256, 0, stream>>>(scoresf, att_bf);
  gemm(1, vw_bf, srcv_bf, nullptr, svt_bf, nullptr, kE, kS, kE, kB,
       0, (long long)kS * kE, (long long)kE * kS, nullptr, nullptr, stream);
  gemm(0, att_bf, svt_bf, retrf, nullptr, nullptr, kT, kE, kS, kB,
       (long long)kT * kS, (long long)kE * kS, (long long)kT * kE,
       nullptr, nullptr, stream);
  gemm(3, states_bf, gatew_bf, nullptr, mixed_bf, gate_b, kB * kT, kE, kH,
       1, 0, 0, 0, basef, retrf, stream);
  gemm(0, mixed_bf, embw_bf, out, nullptr, out_b, kB * kT, kV, kE,
       1, 0, 0, 0, nullptr, nullptr, stream);
}

// Round 16
// 4081.358 us; speedup vs baseline: 1.2004x; 1.1150x over previous
//
#include <hip/hip_runtime.h>
#include <stdint.h>

typedef unsigned short u16;
typedef unsigned int u32;
typedef unsigned long long u64;
using f32x4 = __attribute__((ext_vector_type(4))) float;
using s16x8 = __attribute__((ext_vector_type(8))) short;
using s16x4 = __attribute__((ext_vector_type(4))) short;

#define DI __device__ __forceinline__

constexpr int kV = 32000, kE = 512, kH = 1024, kM = 256;
constexpr int kB = 2, kT = 2048, kS = 512;  // kS = kT/STRIDE, STRIDE=4
constexpr u64 kWatchdogTicks = 200000000ull;  // ~2 s at 100 MHz realtime clock

DI u16 f2bf(float f) {
  u32 u = __float_as_uint(f);
  u32 r = (u + 0x7FFFu + ((u >> 16) & 1u)) >> 16;  // RNE
  return (u16)r;
}
DI float bf2f(u16 u) { return __uint_as_float(((u32)u) << 16); }

DI void gload_lds16(const void* g, void* l) {
  __builtin_amdgcn_global_load_lds((const __attribute__((address_space(1))) void*)g,
                                   (__attribute__((address_space(3))) void*)l, 16, 0, 0);
}
DI bool wd_expired(u64 t0) {
  return (__builtin_amdgcn_s_memrealtime() - t0) > kWatchdogTicks;
}

// ---------------------------------------------------------------- converts
__global__ __launch_bounds__(256)
void k_cvt(const float* __restrict__ in, u16* __restrict__ out, int n) {
  const int step = gridDim.x * blockDim.x;
  for (int i = blockIdx.x * blockDim.x + threadIdx.x; i * 4 < n; i += step) {
    f32x4 v = *(const f32x4*)(in + (size_t)i * 4);
    ushort4 o;
    o.x = f2bf(v[0]); o.y = f2bf(v[1]); o.z = f2bf(v[2]); o.w = f2bf(v[3]);
    *(ushort4*)(out + (size_t)i * 4) = o;
  }
}

__global__ __launch_bounds__(128)
void k_embed(const int* __restrict__ ids, const float* __restrict__ W,
             u16* __restrict__ out) {
  const int tok = blockIdx.x;
  const int id = ids[tok];
  f32x4 v = ((const f32x4*)(W + (size_t)id * kE))[threadIdx.x];
  ushort4 o;
  o.x = f2bf(v[0]); o.y = f2bf(v[1]); o.z = f2bf(v[2]); o.w = f2bf(v[3]);
  ((ushort4*)(out + (size_t)tok * kE))[threadIdx.x] = o;
}

__global__ __launch_bounds__(256)
void k_stride_copy(const u16* __restrict__ in, u16* __restrict__ out, int rowlen) {
  const int row = blockIdx.x;
  const int b = row / kS, s = row - b * kS;
  const u16* src = in + ((size_t)b * kT + 4 * s) * rowlen;
  u16* dst = out + (size_t)row * rowlen;
  for (int i = threadIdx.x; i < rowlen / 2; i += blockDim.x)
    reinterpret_cast<u32*>(dst)[i] = reinterpret_cast<const u32*>(src)[i];
}

// ---------------------------------------------------------------- GEMM
template<int EPI>
__global__ __launch_bounds__(256)
void k_gemm(const u16* __restrict__ A, const u16* __restrict__ Bm,
            float* __restrict__ Cf, u16* __restrict__ Cb,
            const float* __restrict__ bias,
            int Mdim, int Ndim, int Kdim,
            long long sA, long long sB, long long sC,
            const float* __restrict__ addf, const float* __restrict__ mulf) {
  __shared__ __align__(16) u16 lA[128 * 32];
  __shared__ __align__(16) u16 lB[128 * 32];
  const int tid = threadIdx.x;
  const int bz = blockIdx.z;
  A += (long long)bz * sA;
  Bm += (long long)bz * sB;
  const long long coff = (long long)bz * sC;
  const int m0 = blockIdx.y * 128;
  const int n0 = blockIdx.x * 128;
  const int lane = tid & 63;
  const int wm = ((tid >> 6) >> 1) * 64;
  const int wn = ((tid >> 6) & 1) * 64;
  const int sr = tid >> 2;
  const int sc = (tid & 3) * 8;
  f32x4 acc[4][4] = {};
  for (int kt = 0; kt < Kdim; kt += 32) {
    gload_lds16(A + (long long)(m0 + sr) * Kdim + kt + sc,       &lA[tid * 8]);
    gload_lds16(A + (long long)(m0 + 64 + sr) * Kdim + kt + sc,  &lA[(tid + 256) * 8]);
    gload_lds16(Bm + (long long)(n0 + sr) * Kdim + kt + sc,      &lB[tid * 8]);
    gload_lds16(Bm + (long long)(n0 + 64 + sr) * Kdim + kt + sc, &lB[(tid + 256) * 8]);
    __syncthreads();
    s16x8 af[4], bfv[4];
    const int fro = lane & 15;
    const int fk = (lane >> 4) * 8;
#pragma unroll
    for (int f = 0; f < 4; f++) {
      af[f]  = *reinterpret_cast<const s16x8*>(&lA[(wm + f * 16 + fro) * 32 + fk]);
      bfv[f] = *reinterpret_cast<const s16x8*>(&lB[(wn + f * 16 + fro) * 32 + fk]);
    }
#pragma unroll
    for (int i = 0; i < 4; i++)
#pragma unroll
      for (int j = 0; j < 4; j++)
        acc[i][j] = __builtin_amdgcn_mfma_f32_16x16x32_bf16(af[i], bfv[j], acc[i][j], 0, 0, 0);
    __syncthreads();
  }
  const int crow = (lane >> 4) * 4;
  const int ccol = lane & 15;
#pragma unroll
  for (int i = 0; i < 4; i++) {
#pragma unroll
    for (int j = 0; j < 4; j++) {
      const int gn = n0 + wn + j * 16 + ccol;
      const float bs = bias ? bias[gn] : 0.0f;
#pragma unroll
      for (int r = 0; r < 4; r++) {
        const int gm = m0 + wm + i * 16 + crow + r;
        const long long off = coff + (long long)gm * Ndim + gn;
        float v = acc[i][j][r] + bs;
        if constexpr (EPI == 0) {
          Cf[off] = v;
        } else if constexpr (EPI == 1) {
          Cb[off] = f2bf(v);
        } else if constexpr (EPI == 2) {
          float uu = fmaxf(v, 0.0f);
          Cb[off] = f2bf(uu * uu);
        } else {
          float g = 1.0f / (1.0f + __expf(-v));
          Cb[off] = f2bf(addf[off] + g * mulf[off]);
        }
      }
    }
  }
}

// ---------------------------------------------------------------- GRU
// Best-known configuration (round-8): XCD-local domains, tagged-h via
// plain store + nt poll, handshake-with-demotion, ONE barrier/step via
// lh double buffer, per-wave backpressure, poll-count + wall-clock
// watchdog. Weights staged via LDS and extracted to f32 (the compiler
// restreams them per step from L2 -- measured cheaper than every
// residency scheme tried in rounds 9-15).
__global__ __launch_bounds__(512, 2)
void k_gru(const float* __restrict__ xg, const u16* __restrict__ whh,
           const float* __restrict__ bhh, u64* __restrict__ hbuf,
           u32* __restrict__ flags, u16* __restrict__ states) {
  __shared__ __align__(16) u16 lw[48 * 1024];   // 96 KB weight staging
  __shared__ __align__(16) float lh[2][1024];   // h_t double buffer
  __shared__ u32 s_ticket, s_dec, s_res, s_bail;
  const int tid = threadIdx.x;
  const u64 wd0 = __builtin_amdgcn_s_memrealtime();
  u32 xcc;
  asm("s_getreg_b32 %0, hwreg(HW_REG_XCC_ID)" : "=s"(xcc));
  xcc &= 7u;
  if (tid == 0) {
    s_bail = 0u;
    u32 tk = atomicAdd(&flags[128 + xcc], 1u);
    if (tk == 31u) {  // 32nd WG on this XCD -> declare full
      u32 fidx = atomicAdd(&flags[136], 1u);
      if (fidx < 2u)
        __hip_atomic_store(&flags[140 + fidx], xcc + 1u, __ATOMIC_RELAXED, __HIP_MEMORY_SCOPE_AGENT);
    }
    s_ticket = tk;
    u32 d = 0;
    if (blockIdx.x == 0) {
      u32 polls = 0;
      for (;;) {
        if (__hip_atomic_load(&flags[136], __ATOMIC_RELAXED, __HIP_MEMORY_SCOPE_AGENT) >= 2u) {
          u32 a = __hip_atomic_load(&flags[140], __ATOMIC_RELAXED, __HIP_MEMORY_SCOPE_AGENT);
          u32 b = __hip_atomic_load(&flags[141], __ATOMIC_RELAXED, __HIP_MEMORY_SCOPE_AGENT);
          if (a && b) { d = 1u | ((a - 1u) << 8) | ((b - 1u) << 16); break; }
        }
        __builtin_amdgcn_s_sleep(1);
        if (++polls > 500000u || wd_expired(wd0)) { d = 2u; break; }  // fallback
      }
      __hip_atomic_store(&flags[137], d, __ATOMIC_RELAXED, __HIP_MEMORY_SCOPE_AGENT);
    } else {
      u32 polls = 0;
      while (!(d = __hip_atomic_load(&flags[137], __ATOMIC_RELAXED, __HIP_MEMORY_SCOPE_AGENT))) {
        __builtin_amdgcn_s_sleep(1);
        if (++polls > 1000000u || wd_expired(wd0)) { d = 2u; break; }
      }
    }
    s_dec = d;
  }
  __syncthreads();
  const u32 dec = s_dec, ticket = s_ticket;
  int batch = -1;
  u32 slice = 0;
  bool l2m = false;
  if ((dec & 0xFFu) == 1u) {
    const u32 d0 = (dec >> 8) & 0xFFu, d1 = (dec >> 16) & 0xFFu;
    if (xcc == d0 && ticket < 32u) { batch = 0; slice = ticket; l2m = true; }
    else if (xcc == d1 && ticket < 32u) { batch = 1; slice = ticket; l2m = true; }
  } else {
    if (blockIdx.x < 64u) { batch = (int)(blockIdx.x >> 5); slice = blockIdx.x & 31u; }
  }
  if (batch < 0) return;

  // ---- handshake (XCD mode): test plain-store -> nt-load L2 visibility
  if (l2m) {
    u32* hel = &flags[160 + batch * 32];
    u32* vot = &flags[224 + batch * 32];
    if (tid == 0) {
      u32 one = 1u;
      asm volatile("global_store_dword %0, %1, off" :: "v"(&hel[slice]), "v"(one) : "memory");
    }
    bool ok = true;
    if (tid < 32) {
      u32 v = 0, polls = 0;
      const u32* hp = &hel[tid];
      do {
        asm volatile("global_load_dword %0, %1, off nt\n\ts_waitcnt vmcnt(0)"
                     : "=v"(v) : "v"(hp) : "memory");
        if (v) break;
        if (wd_expired(wd0)) break;
      } while (++polls < 200000u);
      ok = (v != 0);
    }
    u64 bad = __ballot(tid < 32 && !ok);
    if (tid == 0)
      __hip_atomic_store(&vot[slice], bad ? 2u : 1u, __ATOMIC_RELAXED, __HIP_MEMORY_SCOPE_AGENT);
    bool vb = false;
    if (tid < 32) {
      u32 v = 0, polls = 0;
      while (!(v = __hip_atomic_load(&vot[tid], __ATOMIC_RELAXED, __HIP_MEMORY_SCOPE_AGENT)))
        if (++polls > 1000000u || wd_expired(wd0)) break;
      vb = (v != 1u);
    }
    u64 anybad = __ballot(tid < 32 && vb);
    if (tid == 0) s_res = (anybad == 0ull) ? 1u : 0u;
    __syncthreads();
    if (s_res == 0u) l2m = false;  // collective demotion to MALL atomics
  }

  // ---- stage 96 W_hh rows (2 halves x 48) via LDS -> f32 extraction
  const int j0 = (int)slice * 32;
  const int grp = tid >> 4;   // 0..31 -> local output j
  const int gl = tid & 15;    // 16 lanes per output
  const int j = j0 + grp;
  f32x4 wreg[3][16];
#pragma unroll
  for (int half = 0; half < 2; half++) {
#pragma unroll
    for (int r = 0; r < 12; r++) {
      int fi = tid + 512 * r;
      int lr = fi >> 7;
      int ce = (fi & 127) * 8;
      int lrow = half * 48 + lr;   // 0..95 = gate*32 + row
      int gate = lrow >> 5, row = lrow & 31;
      gload_lds16(whh + ((size_t)gate * kH + j0 + row) * kH + ce, &lw[fi * 8]);
    }
    __syncthreads();
#pragma unroll
    for (int g = 0; g < 3; g++) {
      const int lrow = g * 32 + grp;
      if (lrow >= half * 48 && lrow < half * 48 + 48) {
        const u16* src = &lw[(size_t)(lrow - half * 48) * 1024];
#pragma unroll
        for (int i = 0; i < 16; i++) {
          s16x4 w = *(const s16x4*)&src[4 * (gl + 16 * i)];
          f32x4 wf;
          wf[0] = bf2f((u16)w[0]); wf[1] = bf2f((u16)w[1]);
          wf[2] = bf2f((u16)w[2]); wf[3] = bf2f((u16)w[3]);
          wreg[g][i] = wf;
        }
      }
    }
    __syncthreads();
  }

  const float bhr = bhh[j], bhz = bhh[kH + j], bhn = bhh[2 * kH + j];
  u32* fl = flags + batch * 64;
  const int fli = tid & 31;
  const float* xgb = xg + (size_t)batch * kT * 3 * kH;
  u16* stb = states + (size_t)batch * kT * kH;
  float hkeep = 0.0f;
  float gi_r = 0.0f, gi_z = 0.0f, gi_n = 0.0f;
  if (gl == 0) { gi_r = xgb[j]; gi_z = xgb[kH + j]; gi_n = xgb[2 * kH + j]; }
  bool bailed = false;

  for (int t = 0; t < kT; t++) {
    u64* hc = hbuf + (size_t)(t & 1) * (kB * kH) + (size_t)batch * kH;
    u64* hn = hbuf + (size_t)((t + 1) & 1) * (kB * kH) + (size_t)batch * kH;
    const u32 want = (u32)t;
    float* lhb = lh[t & 1];
    // ---- stage h_t: poll tagged atoms (2 per thread)
    if (!bailed) {
      u64 v0 = 0, v1 = 0;
      u32 polls = 0;
      if (l2m) {
        const u64* p0 = hc + tid;
        const u64* p1 = hc + tid + 512;
        for (;;) {
          asm volatile(
              "global_load_dwordx2 %0, %2, off nt\n\t"
              "global_load_dwordx2 %1, %3, off nt\n\t"
              "s_waitcnt vmcnt(0)"
              : "=&v"(v0), "=&v"(v1) : "v"(p0), "v"(p1) : "memory");
          if ((u32)(v0 >> 32) >= want && (u32)(v1 >> 32) >= want) break;
          if (++polls > 400000u) { bailed = true; break; }
          if (!(polls & 4095u) && wd_expired(wd0)) { bailed = true; break; }
        }
      } else {
        for (;;) {
          v0 = __hip_atomic_load(hc + tid, __ATOMIC_RELAXED, __HIP_MEMORY_SCOPE_AGENT);
          v1 = __hip_atomic_load(hc + tid + 512, __ATOMIC_RELAXED, __HIP_MEMORY_SCOPE_AGENT);
          if ((u32)(v0 >> 32) >= want && (u32)(v1 >> 32) >= want) break;
          if (++polls > 400000u) { bailed = true; break; }
          if (!(polls & 4095u) && wd_expired(wd0)) { bailed = true; break; }
        }
      }
      lhb[tid] = __uint_as_float((u32)v0);
      lhb[tid + 512] = __uint_as_float((u32)v1);
    }
    if (bailed) s_bail = 1u;   // benign race
    __syncthreads();           // THE barrier: lh ready; all h_t reads done
    bailed = (s_bail != 0u);   // WG-wide sticky
    // release buffer parity for step-t+1 writers
    if (tid == 0) {
      u32 fv = (u32)(t + 1);
      if (l2m) asm volatile("global_store_dword %0, %1, off" :: "v"(&fl[slice]), "v"(fv) : "memory");
      else __hip_atomic_store(&fl[slice], fv, __ATOMIC_RELAXED, __HIP_MEMORY_SCOPE_AGENT);
    }
    // pre-issue backpressure flag read (all lanes; fl[tid&31])
    u32 myf = 0;
    if (!bailed) {
      if (l2m) asm volatile("global_load_dword %0, %1, off nt\n\ts_waitcnt vmcnt(0)"
                            : "=v"(myf) : "v"(&fl[fli]) : "memory");
      else myf = __hip_atomic_load(&fl[fli], __ATOMIC_RELAXED, __HIP_MEMORY_SCOPE_AGENT);
    }
    // ---- dots: 3 gates x 1024 per output, f32 weights
    float ar = 0.f, az = 0.f, an = 0.f;
#pragma unroll
    for (int i = 0; i < 16; i++) {
      f32x4 h4 = *(const f32x4*)&lhb[4 * (gl + 16 * i)];
      f32x4 w0 = wreg[0][i], w1 = wreg[1][i], w2 = wreg[2][i];
#pragma unroll
      for (int e = 0; e < 4; e++) {
        ar += w0[e] * h4[e];
        az += w1[e] * h4[e];
        an += w2[e] * h4[e];
      }
    }
#pragma unroll
    for (int m = 8; m >= 1; m >>= 1) {
      ar += __shfl_xor(ar, m, 16);
      az += __shfl_xor(az, m, 16);
      an += __shfl_xor(an, m, 16);
    }
    // ---- backpressure (per-wave): all domain flags >= t
    if (!bailed) {
      u32 polls = 0;
      while (__ballot(myf < want) != 0ull) {
        if (++polls > 400000u) { bailed = true; break; }
        if (!(polls & 4095u) && wd_expired(wd0)) { bailed = true; break; }
        if (l2m) asm volatile("global_load_dword %0, %1, off nt\n\ts_waitcnt vmcnt(0)"
                              : "=v"(myf) : "v"(&fl[fli]) : "memory");
        else myf = __hip_atomic_load(&fl[fli], __ATOMIC_RELAXED, __HIP_MEMORY_SCOPE_AGENT);
      }
    }
    if (gl == 0) {
      float r = 1.0f / (1.0f + __expf(-(gi_r + ar + bhr)));
      float z = 1.0f / (1.0f + __expf(-(gi_z + az + bhz)));
      float ex = __expf(2.0f * (gi_n + r * (an + bhn)));
      float n = (ex - 1.0f) / (ex + 1.0f);   // tanh
      float hnew = (1.0f - z) * n + z * hkeep;
      hkeep = hnew;
      u64 pk = ((u64)(u32)(t + 1) << 32) | (u64)__float_as_uint(hnew);
      if (l2m) asm volatile("global_store_dwordx2 %0, %1, off" :: "v"(hn + j), "v"(pk) : "memory");
      else __hip_atomic_store(hn + j, pk, __ATOMIC_RELAXED, __HIP_MEMORY_SCOPE_AGENT);
      stb[(size_t)t * kH + j] = f2bf(hnew);
      if (t + 1 < kT) {  // prefetch next xg (hides under next poll)
        const float* xp = xgb + (size_t)(t + 1) * 3 * kH;
        gi_r = xp[j]; gi_z = xp[kH + j]; gi_n = xp[2 * kH + j];
      }
    }
  }
}

// ---------------------------------------------------------------- softmax
__global__ __launch_bounds__(256)
void k_softmax(const float* __restrict__ sc, u16* __restrict__ att) {
  const int row = blockIdx.x * 4 + (threadIdx.x >> 6);
  const int lane = threadIdx.x & 63;
  const int t = row & (kT - 1);
  const int nv = (t + 3) >> 2;
  const float* src = sc + (long long)row * kS;
  u16* dst = att + (long long)row * kS;
  f32x4 v0 = *(const f32x4*)(src + lane * 8);
  f32x4 v1 = *(const f32x4*)(src + lane * 8 + 4);
  float x[8];
  float mx = -3.0e38f;
#pragma unroll
  for (int e = 0; e < 8; e++) {
    float val = ((e < 4) ? v0[e & 3] : v1[e & 3]) * 0.0625f;  // 1/sqrt(256)
    x[e] = val;
    if (lane * 8 + e < nv) mx = fmaxf(mx, val);
  }
#pragma unroll
  for (int m = 32; m >= 1; m >>= 1) mx = fmaxf(mx, __shfl_xor(mx, m, 64));
  float p[8];
  float sum = 0.0f;
#pragma unroll
  for (int e = 0; e < 8; e++) {
    p[e] = (lane * 8 + e < nv) ? __expf(x[e] - mx) : 0.0f;
    sum += p[e];
  }
#pragma unroll
  for (int m = 32; m >= 1; m >>= 1) sum += __shfl_xor(sum, m, 64);
  const float inv = (nv == 0) ? 0.0f : (1.0f / sum);
  ushort4 o0, o1;
  o0.x = f2bf(p[0] * inv); o0.y = f2bf(p[1] * inv);
  o0.z = f2bf(p[2] * inv); o0.w = f2bf(p[3] * inv);
  o1.x = f2bf(p[4] * inv); o1.y = f2bf(p[5] * inv);
  o1.z = f2bf(p[6] * inv); o1.w = f2bf(p[7] * inv);
  *(ushort4*)(dst + lane * 8) = o0;
  *(ushort4*)(dst + lane * 8 + 4) = o1;
}

// ---------------------------------------------------------------- host
static void gemm(int epi, const u16* A, const u16* Bm, float* Cf, u16* Cb,
                 const float* bias, int M, int N, int K, int batch,
                 long long sA, long long sB, long long sC,
                 const float* addf, const float* mulf, hipStream_t st) {
  dim3 g((unsigned)(N / 128), (unsigned)(M / 128), (unsigned)batch), b(256);
  switch (epi) {
    case 0: k_gemm<0><<<g, b, 0, st>>>(A, Bm, Cf, Cb, bias, M, N, K, sA, sB, sC, addf, mulf); break;
    case 1: k_gemm<1><<<g, b, 0, st>>>(A, Bm, Cf, Cb, bias, M, N, K, sA, sB, sC, addf, mulf); break;
    case 2: k_gemm<2><<<g, b, 0, st>>>(A, Bm, Cf, Cb, bias, M, N, K, sA, sB, sC, addf, mulf); break;
    default: k_gemm<3><<<g, b, 0, st>>>(A, Bm, Cf, Cb, bias, M, N, K, sA, sB, sC, addf, mulf); break;
  }
}

extern "C" void kernel_launch(void* const* d_in, const int* in_sizes, int n_in,
                              void* d_out, int out_size, void* d_ws, size_t ws_size,
                              hipStream_t stream) {
  (void)in_sizes; (void)n_in; (void)out_size;
  const int* ids      = (const int*)d_in[0];
  const float* embW   = (const float*)d_in[1];
  const float* w_ih   = (const float*)d_in[2];
  const float* w_hh   = (const float*)d_in[3];
  const float* b_ih   = (const float*)d_in[4];
  const float* b_hh   = (const float*)d_in[5];
  const float* q_w    = (const float*)d_in[6];
  const float* q_b    = (const float*)d_in[7];
  const float* k_w    = (const float*)d_in[8];
  const float* k_b    = (const float*)d_in[9];
  const float* hfc_w  = (const float*)d_in[10];
  const float* hfc_b  = (const float*)d_in[11];
  const float* hproj_w  = (const float*)d_in[12];
  const float* hproj_b  = (const float*)d_in[13];
  const float* v_w    = (const float*)d_in[14];
  const float* gate_w = (const float*)d_in[15];
  const float* gate_b = (const float*)d_in[16];
  const float* out_b  = (const float*)d_in[17];
  float* out = (float*)d_out;

  char* ws = (char*)d_ws;
  size_t off = 0;
  auto alloc = [&](size_t bytes) -> void* {
    void* p = ws + off;
    off += (bytes + 255) & ~(size_t)255;
    return p;
  };
  // ---- persistent region ----
  u16* embw_bf   = (u16*)alloc((size_t)kV * kE * 2);
  u16* states_bf = (u16*)alloc((size_t)kB * kT * kH * 2);
  u16* emb_bf    = (u16*)alloc((size_t)kB * kT * kE * 2);
  u16* qw_bf     = (u16*)alloc((size_t)kM * kH * 2);
  u16* kw_bf     = (u16*)alloc((size_t)kM * kH * 2);
  u16* hfcw_bf   = (u16*)alloc((size_t)4 * kE * kH * 2);
  u16* hprojw_bf = (u16*)alloc((size_t)kE * 4 * kE * 2);
  u16* vw_bf     = (u16*)alloc((size_t)kE * kE * 2);
  u16* gatew_bf  = (u16*)alloc((size_t)kE * kH * 2);
  u64* hbuf      = (u64*)alloc((size_t)2 * kB * kH * 8);   // 32 KB tagged h
  u32* flags     = (u32*)alloc(2048);                      // control block
  const size_t s0 = off;
  // ---- scratch layout G (GRU phase) ----
  u16* wih_bf    = (u16*)alloc((size_t)3 * kH * kE * 2);
  u16* whh_bf    = (u16*)alloc((size_t)3 * kH * kH * 2);
  float* xg      = (float*)alloc((size_t)kB * kT * 3 * kH * 4);
  const size_t endG = off;
  // ---- scratch layout A (attention phase; aliases G) ----
  off = s0;
  u16* head_bf   = (u16*)alloc((size_t)kB * kT * 4 * kE * 2);
  float* basef   = (float*)alloc((size_t)kB * kT * kE * 4);
  u16* qk_bf     = (u16*)alloc((size_t)kB * kT * kM * 2);
  u16* srcs_bf   = (u16*)alloc((size_t)kB * kS * kH * 2);
  u16* srcv_bf   = (u16*)alloc((size_t)kB * kS * kE * 2);
  u16* mk_bf     = (u16*)alloc((size_t)kB * kS * kM * 2);
  float* scoresf = (float*)alloc((size_t)kB * kT * kS * 4);
  u16* att_bf    = (u16*)alloc((size_t)kB * kT * kS * 2);
  u16* svt_bf    = (u16*)alloc((size_t)kB * kE * kS * 2);
  float* retrf   = (float*)alloc((size_t)kB * kT * kE * 4);
  u16* mixed_bf  = (u16*)alloc((size_t)kB * kT * kE * 2);
  const size_t endA = off;
  const size_t need = (endG > endA ? endG : endA);
  if (ws_size < need) return;  // clean failure instead of OOB wedge

  dim3 b256(256);
  k_cvt<<<1024, b256, 0, stream>>>(w_ih, wih_bf, 3 * kH * kE);
  k_cvt<<<1024, b256, 0, stream>>>(w_hh, whh_bf, 3 * kH * kH);
  k_cvt<<<1024, b256, 0, stream>>>(q_w, qw_bf, kM * kH);
  k_cvt<<<1024, b256, 0, stream>>>(k_w, kw_bf, kM * kH);
  k_cvt<<<1024, b256, 0, stream>>>(hfc_w, hfcw_bf, 4 * kE * kH);
  k_cvt<<<1024, b256, 0, stream>>>(hproj_w, hprojw_bf, kE * 4 * kE);
  k_cvt<<<1024, b256, 0, stream>>>(v_w, vw_bf, kE * kE);
  k_cvt<<<1024, b256, 0, stream>>>(gate_w, gatew_bf, kE * kH);
  k_cvt<<<2048, b256, 0, stream>>>(embW, embw_bf, kV * kE);
  k_embed<<<kB * kT, 128, 0, stream>>>(ids, embW, emb_bf);

  // xg = emb @ w_ih^T + b_ih  (f32 out, feeds GRU)
  gemm(0, emb_bf, wih_bf, xg, nullptr, b_ih, kB * kT, 3 * kH, kE,
       1, 0, 0, 0, nullptr, nullptr, stream);

  // GRU scan; tagged h-buffer + control block zeroed (tag 0 == h_0 = 0.0)
  hipMemsetAsync(hbuf, 0, (size_t)2 * kB * kH * 8 + 2048, stream);
  k_gru<<<256, dim3(512), 0, stream>>>(xg, whh_bf, b_hh, hbuf, flags, states_bf);

  gemm(2, states_bf, hfcw_bf, nullptr, head_bf, hfc_b, kB * kT, 4 * kE, kH,
       1, 0, 0, 0, nullptr, nullptr, stream);
  gemm(0, head_bf, hprojw_bf, basef, nullptr, hproj_b, kB * kT, kE, 4 * kE,
       1, 0, 0, 0, nullptr, nullptr, stream);
  gemm(1, states_bf, qw_bf, nullptr, qk_bf, q_b, kB * kT, kM, kH,
       1, 0, 0, 0, nullptr, nullptr, stream);
  k_stride_copy<<<kB * kS, b256, 0, stream>>>(states_bf, srcs_bf, kH);
  k_stride_copy<<<kB * kS, b256, 0, stream>>>(emb_bf, srcv_bf, kE);
  gemm(1, srcs_bf, kw_bf, nullptr, mk_bf, k_b, kB * kS, kM, kH,
       1, 0, 0, 0, nullptr, nullptr, stream);
  gemm(0, qk_bf, mk_bf, scoresf, nullptr, nullptr, kT, kS, kM, kB,
       (long long)kT * kM, (long long)kS * kM, (long long)kT * kS,
       nullptr, nullptr, stream);
  k_softmax<<<(kB * kT) / 4, b256, 0, stream>>>(scoresf, att_bf);
  gemm(1, vw_bf, srcv_bf, nullptr, svt_bf, nullptr, kE, kS, kE, kB,
       0, (long long)kS * kE, (long long)kE * kS, nullptr, nullptr, stream);
  gemm(0, att_bf, svt_bf, retrf, nullptr, nullptr, kT, kE, kS, kB,
       (long long)kT * kS, (long long)kE * kS, (long long)kT * kE,
       nullptr, nullptr, stream);
  gemm(3, states_bf, gatew_bf, nullptr, mixed_bf, gate_b, kB * kT, kE, kH,
       1, 0, 0, 0, basef, retrf, stream);
  gemm(0, mixed_bf, embw_bf, out, nullptr, out_b, kB * kT, kV, kE,
       1, 0, 0, 0, nullptr, nullptr, stream);
}